// Round 3
// baseline (413.118 us; speedup 1.0000x reference)
//
#include <hip/hip_runtime.h>

typedef int v4i __attribute__((ext_vector_type(4)));
typedef int v16i __attribute__((ext_vector_type(16)));

#define BM 256
#define BN 256
#define BKB 64   // K-bytes per ring slot (i8 elems). 64 B rows.
#define NRING 4  // 4 slots x (16KB A + 16KB B) = 128 KB LDS, prefetch distance 3

// async global->LDS, 16B per lane. LDS dest = wave-uniform base + lane*16.
#define GLOAD_LDS(gptr, lptr)                                                         \
  __builtin_amdgcn_global_load_lds(                                                   \
      (const __attribute__((address_space(1))) unsigned int*)(gptr),                  \
      (__attribute__((address_space(3))) unsigned int*)(lptr), 16, 0, 0)

// ---------- preprocessing ----------

__device__ __forceinline__ float max4abs(float4 v) {
  return fmaxf(fmaxf(fabsf(v.x), fabsf(v.y)), fmaxf(fabsf(v.z), fabsf(v.w)));
}

__device__ __forceinline__ int packq4(float4 v, float inv) {
  int b0 = ((int)fminf(127.f, fmaxf(-127.f, rintf(v.x * inv)))) & 255;
  int b1 = ((int)fminf(127.f, fmaxf(-127.f, rintf(v.y * inv)))) & 255;
  int b2 = ((int)fminf(127.f, fmaxf(-127.f, rintf(v.z * inv)))) & 255;
  int b3 = ((int)fminf(127.f, fmaxf(-127.f, rintf(v.w * inv)))) & 255;
  return b0 | (b1 << 8) | (b2 << 16) | (b3 << 24);
}

// Fused: blocks [0,nrows) per-row i8-quantize x; blocks [nrows,nrows+1024) reduce
// max|W|; last block reduces max|b|. All independent -> one dispatch.
__global__ void prep1_kernel(const float4* __restrict__ X4,
                             signed char* __restrict__ Q,
                             float* __restrict__ sx, int K, int nrows,
                             const float4* __restrict__ W4, long nW4,
                             const float4* __restrict__ b4, int nb4,
                             unsigned* __restrict__ mx) {
  __shared__ float sm[4];
  const int tid = threadIdx.x;
  const int bid = blockIdx.x;

  if (bid < nrows) {  // ---- xquant: one block per row, K==4096 assumed
    const float4* xr = X4 + (size_t)bid * (K / 4);
    float4 v0 = xr[tid], v1 = xr[tid + 256], v2 = xr[tid + 512], v3 = xr[tid + 768];
    float m = fmaxf(fmaxf(max4abs(v0), max4abs(v1)), fmaxf(max4abs(v2), max4abs(v3)));
    for (int off = 32; off > 0; off >>= 1) m = fmaxf(m, __shfl_down(m, off));
    if ((tid & 63) == 0) sm[tid >> 6] = m;
    __syncthreads();
    const float total = fmaxf(fmaxf(sm[0], sm[1]), fmaxf(sm[2], sm[3]));
    const float inv = 127.f / total;
    int* qw = (int*)(Q + (size_t)bid * K);
    qw[tid]       = packq4(v0, inv);
    qw[tid + 256] = packq4(v1, inv);
    qw[tid + 512] = packq4(v2, inv);
    qw[tid + 768] = packq4(v3, inv);
    if (tid == 0) sx[bid] = total * (1.f / 127.f);
    return;
  }

  // ---- absmax reductions
  float m = 0.f;
  const bool isB = (bid == gridDim.x - 1);
  if (!isB) {
    const long wb = bid - nrows;           // 0..1023
    const long stride = 1024L * blockDim.x;
    for (long i = wb * blockDim.x + tid; i < nW4; i += stride)
      m = fmaxf(m, max4abs(W4[i]));
  } else {
    for (int i = tid; i < nb4; i += blockDim.x) m = fmaxf(m, max4abs(b4[i]));
  }
  for (int off = 32; off > 0; off >>= 1) m = fmaxf(m, __shfl_down(m, off));
  if ((tid & 63) == 0) sm[tid >> 6] = m;
  __syncthreads();
  if (tid == 0) {
    m = fmaxf(fmaxf(sm[0], sm[1]), fmaxf(sm[2], sm[3]));
    atomicMax(mx + (isB ? 1 : 0), __float_as_uint(m));  // nonneg: uint order == float
  }
}

// Ternarize W -> i8{-1,0,1} (packed dword per float4, coalesced); last block: b -> fp32.
__global__ void prep_w_kernel(const float4* __restrict__ W4, long nW4,
                              const float4* __restrict__ b4, int nb4,
                              const unsigned* __restrict__ mx,
                              const float* __restrict__ bscale,
                              int* __restrict__ Twi, float4* __restrict__ bt) {
  if (blockIdx.x == gridDim.x - 1) {  // bias block
    const float delta = 0.05f * __uint_as_float(mx[1]);
    const float s = *bscale;
    for (int i = threadIdx.x; i < nb4; i += blockDim.x) {
      float4 v = b4[i];
      float4 o;
      o.x = v.x > delta ? s : (v.x < -delta ? -s : 0.f);
      o.y = v.y > delta ? s : (v.y < -delta ? -s : 0.f);
      o.z = v.z > delta ? s : (v.z < -delta ? -s : 0.f);
      o.w = v.w > delta ? s : (v.w < -delta ? -s : 0.f);
      bt[i] = o;
    }
    return;
  }
  const float delta = 0.05f * __uint_as_float(mx[0]);
  const long stride = (long)(gridDim.x - 1) * blockDim.x;
  for (long i = blockIdx.x * (long)blockDim.x + threadIdx.x; i < nW4; i += stride) {
    float4 w = W4[i];
    int b0 = w.x > delta ? 1 : (w.x < -delta ? 0xFF : 0);
    int b1 = w.y > delta ? 1 : (w.y < -delta ? 0xFF : 0);
    int b2 = w.z > delta ? 1 : (w.z < -delta ? 0xFF : 0);
    int b3 = w.w > delta ? 1 : (w.w < -delta ? 0xFF : 0);
    Twi[i] = b0 | (b1 << 8) | (b2 << 16) | (b3 << 24);
  }
}

// ---------- GEMM: C[m,n] = ws*sx[m]*(sum_k Aq[m,k]*T[n,k]) + bt[n], exact i32 acc ----
// 256x256 tile, 8 waves (2Mx4N), wave tile 128x64 via 4x2 grid of 32x32x32 i8 MFMAs
// (2 k-subs per BKB=64). Ring of 4 LDS slots, prefetch dist 3, one vmcnt(4)+barrier
// per K-step (R1 skeleton — R2's per-phase barriers regressed).
// Cross-step pipeline: MFMAs of step t consume B-fragments read at step t-1 (bf
// ping-pong), A-fragments read early in-step and consumed progressively (in-order
// lgkm => first MFMA waits only for the first ds_read). Matrix pipe is fed from
// barrier release while this step's 12 ds_read_b128 stream through the LDS pipe.
// Residency guarantee: each wave's vmcnt(4)-before-barrier at step T => after that
// barrier ALL waves' stages for slots <= T+2 have landed (collective guarantee).
__global__ __launch_bounds__(512, 2) void gemm_tern_i8(
    const signed char* __restrict__ A,   // [M,K] i8 quantized x
    const signed char* __restrict__ B,   // [N,K] i8 ternary {-1,0,1}
    const float* __restrict__ sx,        // [M] per-row x scale
    const float* __restrict__ bt,        // [N]
    const float* __restrict__ wsc,       // scalar
    float* __restrict__ C,               // [M,N] fp32
    int M, int N, int K) {
  __shared__ __align__(16) signed char lds[NRING][2][BM * BKB];  // 128 KB

  const int tid = threadIdx.x;
  const int wave = tid >> 6;
  const int lane = tid & 63;
  const int wm = wave >> 2, wn = wave & 3;  // 2 x 4 wave grid
  const int l32 = lane & 31;
  const int khalf = lane >> 5;  // 0..1 -> 16B k-chunk within k-sub

  // XCD-aware bijective swizzle: 512 wgs, 8 XCDs -> 64 wgs each = 4-M-row band,
  // column-major inside (kept from R2: FETCH 147->98 MB).
  const unsigned orig = blockIdx.x;
  const unsigned xcd = orig & 7;
  const unsigned r8 = orig >> 3;            // 0..63
  const int by = (int)(xcd * 4 + (r8 & 3)); // 0..31  (M)
  const int bx = (int)(r8 >> 2);            // 0..15  (N)
  const int bm0 = by * BM;
  const int bn0 = bx * BN;

  // staging: 1024 16B-chunks per matrix per tile; thread covers idx = j*512 + tid.
  // row = idx>>2, global chunk = (idx&3) ^ ((idx>>3)&3); LDS dest linear => LDS
  // position p in row r holds global chunk p ^ ((r>>1)&3).
  const signed char* gA[2];
  const signed char* gB[2];
#pragma unroll
  for (int j = 0; j < 2; ++j) {
    const int idx = j * 512 + tid;
    const int row = idx >> 2;
    const int gch = (idx & 3) ^ ((idx >> 3) & 3);
    gA[j] = A + (size_t)(bm0 + row) * K + gch * 16;
    gB[j] = B + (size_t)(bn0 + row) * K + gch * 16;
  }
  const int ldsbase = wave * 64 * 16;  // wave-uniform; HW adds lane*16

#define STAGE(slot)                                  \
  do {                                               \
    signed char* la = &lds[slot][0][ldsbase];        \
    signed char* lb = &lds[slot][1][ldsbase];        \
    GLOAD_LDS(gA[0], la);                            \
    GLOAD_LDS(gA[1], la + 8192);                     \
    GLOAD_LDS(gB[0], lb);                            \
    GLOAD_LDS(gB[1], lb + 8192);                     \
    gA[0] += BKB; gA[1] += BKB;                      \
    gB[0] += BKB; gB[1] += BKB;                      \
  } while (0)

  // 32x32x32 i8 fragment addressing: lane reads row = tilebase + l32, global
  // 16B-chunk c = khalf + 2*ksub -> swizzled LDS pos = c ^ ((l32>>1)&3)
  // (row>>1)&3 == (l32>>1)&3 since tile bases are multiples of 32.
  const int q = (l32 >> 1) & 3;
  const int pos0 = (khalf + 0) ^ q;  // ksub 0
  const int pos1 = (khalf + 2) ^ q;  // ksub 1
  const int aoff0 = (wm * 128 + l32) * BKB + pos0 * 16;  // + mt*2048
  const int aoff1 = (wm * 128 + l32) * BKB + pos1 * 16;
  const int boff0 = (wn * 64 + l32) * BKB + pos0 * 16;   // + nt*2048
  const int boff1 = (wn * 64 + l32) * BKB + pos1 * 16;

  v16i acc[4][2] = {};
  v4i bfA[2][2], bfB[2][2];  // [nt][ksub] ping-pong across K-steps

  const int NT = K / BKB;  // 64 (even, >= 8)

  STAGE(0); STAGE(1); STAGE(2);
  asm volatile("s_waitcnt vmcnt(4)" ::: "memory");  // slots 0,1 landed; slot 2 in flight
  asm volatile("s_barrier" ::: "memory");           // collective: slots 0,1 resident

  // prologue: B-fragments of slot 0 into bfA
#pragma unroll
  for (int nt = 0; nt < 2; ++nt) {
    bfA[nt][0] = *(const v4i*)(&lds[0][1][0] + boff0 + nt * 2048);
    bfA[nt][1] = *(const v4i*)(&lds[0][1][0] + boff1 + nt * 2048);
  }

#define BODY(T, CUR, NXT)                                                              \
  do {                                                                                 \
    const int slot_ = (T) & 3;                                                         \
    if ((T) + 3 < NT) STAGE(((T) + 3) & 3);                                            \
    const signed char* sa_ = &lds[slot_][0][0];                                        \
    v4i af_[4][2];                                                                     \
    _Pragma("unroll")                                                                  \
    for (int mt = 0; mt < 4; ++mt) {                                                   \
      af_[mt][0] = *(const v4i*)(sa_ + aoff0 + mt * 2048);                             \
      af_[mt][1] = *(const v4i*)(sa_ + aoff1 + mt * 2048);                             \
    }                                                                                  \
    if ((T) + 1 < NT) {                                                                \
      const signed char* sbn_ = &lds[((T) + 1) & 3][1][0];                             \
      _Pragma("unroll")                                                                \
      for (int nt = 0; nt < 2; ++nt) {                                                 \
        NXT[nt][0] = *(const v4i*)(sbn_ + boff0 + nt * 2048);                          \
        NXT[nt][1] = *(const v4i*)(sbn_ + boff1 + nt * 2048);                          \
      }                                                                                \
    }                                                                                  \
    __builtin_amdgcn_s_setprio(1);                                                     \
    _Pragma("unroll")                                                                  \
    for (int mt = 0; mt < 4; ++mt)                                                     \
      _Pragma("unroll")                                                                \
      for (int nt = 0; nt < 2; ++nt) {                                                 \
        acc[mt][nt] = __builtin_amdgcn_mfma_i32_32x32x32_i8(af_[mt][0], CUR[nt][0],    \
                                                            acc[mt][nt], 0, 0, 0);    \
        acc[mt][nt] = __builtin_amdgcn_mfma_i32_32x32x32_i8(af_[mt][1], CUR[nt][1],    \
                                                            acc[mt][nt], 0, 0, 0);    \
      }                                                                                \
    __builtin_amdgcn_s_setprio(0);                                                     \
    asm volatile("s_waitcnt vmcnt(4)" ::: "memory");                                   \
    asm volatile("s_barrier" ::: "memory");                                            \
  } while (0)

  // main loop: steps 0..NT-3 (staging active; counted-vmcnt guarantee holds)
  for (int t = 0; t < NT - 2; t += 2) {
    BODY(t, bfA, bfB);
    BODY(t + 1, bfB, bfA);
  }
  // tail: staging stopped -> counted guarantee degenerates; drain once, collectively
  asm volatile("s_waitcnt vmcnt(0)" ::: "memory");
  asm volatile("s_barrier" ::: "memory");
  BODY(NT - 2, bfA, bfB);
  BODY(NT - 1, bfB, bfA);
#undef BODY
#undef STAGE

  // epilogue: 32x32 D layout col = lane&31, row = (r&3) + 8*(r>>2) + 4*(lane>>5)
  const float ws = *wsc;
#pragma unroll
  for (int mt = 0; mt < 4; ++mt) {
    const int rowbase = bm0 + wm * 128 + mt * 32 + 4 * khalf;
#pragma unroll
    for (int nt = 0; nt < 2; ++nt) {
      const int col = bn0 + wn * 64 + nt * 32 + l32;
      const float bias = bt[col];
#pragma unroll
      for (int r = 0; r < 16; ++r) {
        const int row = rowbase + (r & 3) + 8 * (r >> 2);
        C[(size_t)row * N + col] = ws * sx[row] * (float)acc[mt][nt][r] + bias;
      }
    }
  }
}

// ---------- launch ----------

extern "C" void kernel_launch(void* const* d_in, const int* in_sizes, int n_in,
                              void* d_out, int out_size, void* d_ws, size_t ws_size,
                              hipStream_t stream) {
  const float* x = (const float*)d_in[0];
  const float* W = (const float*)d_in[1];
  const float* w_scale = (const float*)d_in[2];
  const float* b = (const float*)d_in[3];
  const float* b_scale = (const float*)d_in[4];
  float* out = (float*)d_out;

  const int K = 4096;             // D_IN
  const int N = in_sizes[3];      // D_OUT = 4096
  const int M = in_sizes[0] / K;  // B*S = 8192

  // workspace layout
  char* ws = (char*)d_ws;
  signed char* xb = (signed char*)ws;                        // M*K i8 (32 MB)
  signed char* Tw = (signed char*)(ws + (size_t)M * K);      // N*K i8 (16 MB)
  float* bt = (float*)(ws + (size_t)M * K + (size_t)N * K);  // N fp32
  float* sx = bt + N;                                        // M fp32
  unsigned* mx = (unsigned*)(sx + M);                        // [0]=max|W|,[1]=max|b|

  hipMemsetAsync(mx, 0, 8, stream);

  const long nW4 = (long)N * K / 4;
  const int nb4 = N / 4;

  // fused xquant + absmax(W) + absmax(b): 8192 + 1024 + 1 blocks
  prep1_kernel<<<M + 1024 + 1, 256, 0, stream>>>((const float4*)x, xb, sx, K, M,
                                                 (const float4*)W, nW4,
                                                 (const float4*)b, nb4, mx);

  prep_w_kernel<<<2049, 256, 0, stream>>>((const float4*)W, nW4,
                                          (const float4*)b, nb4, mx, b_scale,
                                          (int*)Tw, (float4*)bt);

  const int nwg = (N / BN) * (M / BM);  // 512, divisible by 8
  gemm_tern_i8<<<nwg, 512, 0, stream>>>(xb, Tw, sx, bt, w_scale, out, M, N, K);
}